// Round 4
// baseline (288.063 us; speedup 1.0000x reference)
//
#include <hip/hip_runtime.h>

typedef float f32x4 __attribute__((ext_vector_type(4)));
typedef short s16x8 __attribute__((ext_vector_type(8)));
typedef unsigned short u16;

#define N_COLS 4096
#define RANK 64
#define H2S 68   // padded LDS row stride (floats): breaks 64-stride bank aliasing, keeps 16B align

__device__ __forceinline__ unsigned f_asuint(float f) { union { float f; unsigned u; } v; v.f = f; return v.u; }
__device__ __forceinline__ float f_asfloat(unsigned u) { union { unsigned u; float f; } v; v.u = u; return v.f; }
// fp32 -> bf16 round-to-nearest-even
__device__ __forceinline__ short f2bf(float f) {
  unsigned u = f_asuint(f);
  return (short)((u + 0x7fffu + ((u >> 16) & 1u)) >> 16);
}

// ---------------------------------------------------------------------------
// Kernel 0: W[r][n] = b_q[n/64][r] * c_q_t[r][n%64] (bf16, [64][4096])
//           a_bf[m][r] = bf16(a_q[m][r])            (bf16, [4096][64])
// ---------------------------------------------------------------------------
__global__ __launch_bounds__(256) void k_prep(const float* __restrict__ b_q,
                                              const float* __restrict__ c_q_t,
                                              const float* __restrict__ a_q,
                                              u16* __restrict__ W,
                                              u16* __restrict__ a_bf) {
  int idx = blockIdx.x * 256 + threadIdx.x;   // 2*262144 total
  if (idx < RANK * N_COLS) {
    int r = idx >> 12;
    int n = idx & 4095;
    W[idx] = (u16)f2bf(b_q[(n >> 6) * RANK + r] * c_q_t[(r << 6) + (n & 63)]);
  } else {
    int j = idx - RANK * N_COLS;
    a_bf[j] = (u16)f2bf(a_q[j]);
  }
}

// ---------------------------------------------------------------------------
// Fused kernel: per block of 16 tokens —
//  phase 1: fake-NVFP4 quant of (x*smooth) + h2 = xq @ W^T (8-wave K-split 512,
//           LDS reduce, h2 kept fp32 in LDS — never touches HBM)
//  phase 2: out[16][4096] = bf16(h2) @ a_bf^T + bias; each wave owns a 512-m
//           strip, LDS transpose -> contiguous 256B row-segment NT stores.
// Read stream (x) and write stream (out) from co-resident blocks overlap on HBM.
// ---------------------------------------------------------------------------
__global__ __launch_bounds__(512, 4) void k_fused(const float* __restrict__ x,
                                                  const float* __restrict__ smooth,
                                                  const u16* __restrict__ W,
                                                  const u16* __restrict__ a_bf,
                                                  const float* __restrict__ bias,
                                                  float* __restrict__ out) {
  // smem: phase 1 uses it as red[8][16][64] (stride 64); phase 2 as 8 per-wave
  // 16x68 transpose tiles. h2f is the block's fp32 h2 [16][68].
  __shared__ float smem[8 * 16 * H2S];   // 34.8 KB
  __shared__ float h2f[16 * H2S];        //  4.4 KB

  const int t0 = blockIdx.x * 16;
  const int wave = threadIdx.x >> 6;   // 0..7
  const int lane = threadIdx.x & 63;
  const int quad = lane >> 4;
  const int tl = lane & 15;

  // ======================= phase 1: quant + GEMM1 ==========================
  {
    const int K0 = wave * 512 + quad * 8;
    const float* xp = x + (size_t)(t0 + tl) * N_COLS + K0;
    const float* sp = smooth + K0;
    const u16* wp0 = W + (size_t)tl * N_COLS + K0;
    const u16* wp1 = wp0 + 16 * N_COLS;
    const u16* wp2 = wp0 + 32 * N_COLS;
    const u16* wp3 = wp0 + 48 * N_COLS;

    f32x4 acc0 = {0.f, 0.f, 0.f, 0.f};
    f32x4 acc1 = {0.f, 0.f, 0.f, 0.f};
    f32x4 acc2 = {0.f, 0.f, 0.f, 0.f};
    f32x4 acc3 = {0.f, 0.f, 0.f, 0.f};

    for (int s = 0; s < 16; ++s) {
      const int o = s * 32;
      f32x4 xa = __builtin_nontemporal_load(reinterpret_cast<const f32x4*>(xp + o));
      f32x4 xb = __builtin_nontemporal_load(reinterpret_cast<const f32x4*>(xp + o + 4));
      f32x4 sa = *reinterpret_cast<const f32x4*>(sp + o);
      f32x4 sb = *reinterpret_cast<const f32x4*>(sp + o + 4);
      float xs[8];
      xs[0] = xa.x * sa.x; xs[1] = xa.y * sa.y; xs[2] = xa.z * sa.z; xs[3] = xa.w * sa.w;
      xs[4] = xb.x * sb.x; xs[5] = xb.y * sb.y; xs[6] = xb.z * sb.z; xs[7] = xb.w * sb.w;

      // amax over the 16-block: 8 local + partner half in lane^16 (same token)
      float amax = fabsf(xs[0]);
#pragma unroll
      for (int j = 1; j < 8; ++j) amax = fmaxf(amax, fabsf(xs[j]));
      amax = fmaxf(amax, __shfl_xor(amax, 16));
      float scale = fmaxf(amax * (1.0f / 6.0f), 1e-8f);

      // searchsorted(mids, |y|, 'right') == count(|x| >= mid*scale)
      const float th0 = 0.25f * scale, th1 = 0.75f * scale, th2 = 1.25f * scale,
                  th3 = 1.75f * scale, th4 = 2.5f * scale, th5 = 3.5f * scale,
                  th6 = 5.0f * scale;
      s16x8 af;
#pragma unroll
      for (int j = 0; j < 8; ++j) {
        float ax = fabsf(xs[j]);
        float q = (ax >= th0) ? 0.5f : 0.0f;
        q = (ax >= th1) ? 1.0f : q;
        q = (ax >= th2) ? 1.5f : q;
        q = (ax >= th3) ? 2.0f : q;
        q = (ax >= th4) ? 3.0f : q;
        q = (ax >= th5) ? 4.0f : q;
        q = (ax >= th6) ? 6.0f : q;
        float xq = q * scale;
        xq = f_asfloat(f_asuint(xq) | (f_asuint(xs[j]) & 0x80000000u));
        af[j] = f2bf(xq);
      }

      s16x8 b0 = *reinterpret_cast<const s16x8*>(wp0 + o);
      s16x8 b1 = *reinterpret_cast<const s16x8*>(wp1 + o);
      s16x8 b2 = *reinterpret_cast<const s16x8*>(wp2 + o);
      s16x8 b3 = *reinterpret_cast<const s16x8*>(wp3 + o);

      acc0 = __builtin_amdgcn_mfma_f32_16x16x32_bf16(af, b0, acc0, 0, 0, 0);
      acc1 = __builtin_amdgcn_mfma_f32_16x16x32_bf16(af, b1, acc1, 0, 0, 0);
      acc2 = __builtin_amdgcn_mfma_f32_16x16x32_bf16(af, b2, acc2, 0, 0, 0);
      acc3 = __builtin_amdgcn_mfma_f32_16x16x32_bf16(af, b3, acc3, 0, 0, 0);
    }

    // cross-wave reduction of 8 K-split partials (red layout: stride-64 rows)
    float* rw = smem + wave * 1024 + (quad * 4) * 64 + tl;
#pragma unroll
    for (int reg = 0; reg < 4; ++reg) {
      rw[reg * 64 + 0]  = acc0[reg];
      rw[reg * 64 + 16] = acc1[reg];
      rw[reg * 64 + 32] = acc2[reg];
      rw[reg * 64 + 48] = acc3[reg];
    }
  }
  __syncthreads();
  if (threadIdx.x < 256) {
    const f32x4* r4 = reinterpret_cast<const f32x4*>(smem);
    f32x4 v = r4[threadIdx.x];
#pragma unroll
    for (int p = 1; p < 8; ++p) {
      f32x4 u = r4[p * 256 + threadIdx.x];
      v.x += u.x; v.y += u.y; v.z += u.z; v.w += u.w;
    }
    int t = threadIdx.x >> 4;          // token 0..15
    int rr = (threadIdx.x & 15) * 4;   // r offset
    *reinterpret_cast<f32x4*>(h2f + t * H2S + rr) = v;
  }
  __syncthreads();   // h2f visible to all; smem (red) free for reuse

  // ======================= phase 2: out = h2 @ a_bf^T + bias ===============
  // A fragments (16 tokens x K=64, two K-halves), loaded once per wave
  f32x4 a0 = *reinterpret_cast<const f32x4*>(h2f + tl * H2S + quad * 8);
  f32x4 a1 = *reinterpret_cast<const f32x4*>(h2f + tl * H2S + quad * 8 + 4);
  f32x4 a2 = *reinterpret_cast<const f32x4*>(h2f + tl * H2S + 32 + quad * 8);
  f32x4 a3 = *reinterpret_cast<const f32x4*>(h2f + tl * H2S + 32 + quad * 8 + 4);
  s16x8 af_lo, af_hi;
  af_lo[0] = f2bf(a0.x); af_lo[1] = f2bf(a0.y); af_lo[2] = f2bf(a0.z); af_lo[3] = f2bf(a0.w);
  af_lo[4] = f2bf(a1.x); af_lo[5] = f2bf(a1.y); af_lo[6] = f2bf(a1.z); af_lo[7] = f2bf(a1.w);
  af_hi[0] = f2bf(a2.x); af_hi[1] = f2bf(a2.y); af_hi[2] = f2bf(a2.z); af_hi[3] = f2bf(a2.w);
  af_hi[4] = f2bf(a3.x); af_hi[5] = f2bf(a3.y); af_hi[6] = f2bf(a3.z); af_hi[7] = f2bf(a3.w);

  float* wtile = smem + wave * (16 * H2S);   // per-wave private 16x68 tile

  for (int mg = 0; mg < 8; ++mg) {
    const int m_base = wave * 512 + mg * 64;
    f32x4 acc[4] = {};
#pragma unroll
    for (int sub = 0; sub < 4; ++sub) {
      const u16* ap = a_bf + (size_t)(m_base + sub * 16 + tl) * RANK + quad * 8;
      s16x8 blo = *reinterpret_cast<const s16x8*>(ap);
      s16x8 bhi = *reinterpret_cast<const s16x8*>(ap + 32);
      acc[sub] = __builtin_amdgcn_mfma_f32_16x16x32_bf16(af_lo, blo, acc[sub], 0, 0, 0);
      acc[sub] = __builtin_amdgcn_mfma_f32_16x16x32_bf16(af_hi, bhi, acc[sub], 0, 0, 0);
    }
    __syncthreads();   // previous iteration's tile reads complete (mg==0: phase1 done)
#pragma unroll
    for (int sub = 0; sub < 4; ++sub)
#pragma unroll
      for (int reg = 0; reg < 4; ++reg)
        wtile[(quad * 4 + reg) * H2S + sub * 16 + tl] = acc[sub][reg];
    __syncthreads();   // tile writes visible
#pragma unroll
    for (int i = 0; i < 4; ++i) {
      int idx = lane + i * 64;           // 256 float4 = 16 x 64 tile
      int row = idx >> 4;
      int c4 = (idx & 15) << 2;
      f32x4 v = *reinterpret_cast<const f32x4*>(wtile + row * H2S + c4);
      f32x4 b = *reinterpret_cast<const f32x4*>(bias + m_base + c4);
      f32x4 ov;
      ov.x = v.x + b.x; ov.y = v.y + b.y; ov.z = v.z + b.z; ov.w = v.w + b.w;
      __builtin_nontemporal_store(ov,
        reinterpret_cast<f32x4*>(out + (size_t)(t0 + row) * N_COLS + m_base + c4));
    }
  }
}

// ---------------------------------------------------------------------------
extern "C" void kernel_launch(void* const* d_in, const int* in_sizes, int n_in,
                              void* d_out, int out_size, void* d_ws, size_t ws_size,
                              hipStream_t stream) {
  const float* x      = (const float*)d_in[0];
  const float* smooth = (const float*)d_in[1];
  const float* a_q    = (const float*)d_in[2];
  const float* b_q    = (const float*)d_in[3];
  const float* c_q_t  = (const float*)d_in[4];
  const float* bias   = (const float*)d_in[5];
  float* out = (float*)d_out;

  const int T = in_sizes[0] / N_COLS;  // 8192 tokens

  u16* W    = (u16*)d_ws;                    // 512 KB
  u16* a_bf = (u16*)((char*)d_ws + 524288);  // 512 KB

  k_prep<<<2048, 256, 0, stream>>>(b_q, c_q_t, a_q, W, a_bf);
  k_fused<<<T / 16, 512, 0, stream>>>(x, smooth, W, a_bf, bias, out);
}